// Round 7
// baseline (194.946 us; speedup 1.0000x reference)
//
#include <hip/hip_runtime.h>
#include <hip/hip_bf16.h>

// PLELayer round-7: LDS layout surgery (math identical to round-6).
// - xsA pitch 48->52 words: A-frag ds_read_b128 start banks uniform (was
//   8-way conflicted at pitch 48: (48*c16)%32=16*c16).
// - H staging: 4x ds_write_b64 (was 8x b32) via joint k-permutation
//   pi2(s)=(s&3)*16+(s>>2) applied to BOTH H storage and W2's pre-swizzled
//   k-order (sum over k is permutation-invariant).
// - ob transposed to element-major [64e][68 words]: gates/mixing phases read
//   7x ds_read_b128 instead of 28x b32. Pitch 68 = 16B-aligned rows.
// - phase-0 x write and phase-2 l1in writes vectorized to ds_write_b128.

#define NT 256
#define EPB 64

typedef unsigned short u16;
typedef unsigned int u32;
typedef __attribute__((ext_vector_type(8))) short short8;   // 8 bf16
typedef __attribute__((ext_vector_type(4))) float floatx4;

__device__ __forceinline__ float bflo(u32 w){ return __uint_as_float(w << 16); }
__device__ __forceinline__ float bfhi(u32 w){ return __uint_as_float(w & 0xffff0000u); }
__device__ __forceinline__ u32 f2bf(float f){
  u32 v = __float_as_uint(f);
  return (v + 0x7fffu + ((v>>16)&1u)) >> 16;
}
__device__ __forceinline__ u32 pk2(float a, float b){
  __hip_bfloat162 h2 = __float22bfloat162_rn(make_float2(a, b));
  u32 r; __builtin_memcpy(&r, &h2, sizeof(r)); return r;
}

// pi2: H storage-k s -> real h (both levels). Storage word w=2c16+p holds
// (t=2p, t=2p+1)? No: s=4*c16+t -> h = t*16 + c16.
__device__ __forceinline__ int pi2(int s){
  return (s & 3)*16 + (s >> 2);
}

// ---- ws layout ----
#define W1F0 0          // [16u][3s][4t][64l][4]  = 49152
#define W2F0 49152      // [16u][2ks][64l][4]     =  8192
#define W1F1 57344      // [15u][4t][64l][4]      = 15360
#define W2F1 72704      // [15u][2ks][64l][4]     =  7680
#define OFF_b1P0 80384  // [16][64]
#define OFF_b2P0 81408  // [16][16] cols 8..15 zero
#define OFF_b1P1 81664  // [15][64]
#define OFF_b2P1 82624  // [15][16] cols 8..15 zero
#define OFF_G0W3 82864  // [3][8][6]
#define OFF_SG0W3 83008 // [8][12]
#define OFF_G1W3 83104  // [3][8][6]
#define OFF_TW   83248  // [3][8]
#define OFF_Tb   83272  // [3]
#define CVT_TOTAL 83275

struct PSrc { const float* p[33]; };

__global__ void cvt_kernel(PSrc S, u32* __restrict__ wsU, float* __restrict__ wsF){
  int i = blockIdx.x*256 + threadIdx.x;
  if (i >= CVT_TOTAL) return;
  if (i < 49152){  // W1F0: B[k=s*32+q*8+j][h=t*16+c16], k>=72 -> 0
    int j2 = i & 3, l = (i>>2)&63, tt = (i>>8)&3;
    int rest = i >> 10; int s = rest % 3, u = rest / 3;
    int k0 = s*32 + (l>>4)*8 + 2*j2;
    int h  = tt*16 + (l&15);
    const float* src = (u<9)  ? S.p[0]  + (u*72)*64
                     : (u<12) ? S.p[4]  + ((u-9)*72)*64
                     : (u<15) ? S.p[8]  + ((u-12)*72)*64
                              : S.p[13];
    float lo = (k0   < 72) ? src[(k0  )*64 + h] : 0.f;
    float hi = (k0+1 < 72) ? src[(k0+1)*64 + h] : 0.f;
    wsU[i] = pk2(lo, hi);
    return;
  }
  i -= 49152;
  if (i < 8192){   // W2F0: pi2-permuted k, n>=8 -> 0
    int j2 = i & 3, l = (i>>2)&63, ks = (i>>8)&1, u = i>>9;
    int s0 = ks*32 + (l>>4)*8 + 2*j2;
    int n = l & 15;
    const float* src = (u<9)  ? S.p[2]  + u*512
                     : (u<12) ? S.p[6]  + (u-9)*512
                     : (u<15) ? S.p[10] + (u-12)*512
                              : S.p[15];
    float lo = (n<8) ? src[pi2((s0  )&63)*8 + n] : 0.f;
    float hi = (n<8) ? src[pi2((s0+1)&63)*8 + n] : 0.f;
    wsU[W2F0 + i] = pk2(lo, hi);
    return;
  }
  i -= 8192;
  if (i < 15360){  // W1F1: B[k=q*8+j][n=t*16+c16], k>=8 -> 0
    int j2 = i & 3, l = (i>>2)&63, tt = (i>>8)&3, u = i>>10;
    int k0 = (l>>4)*8 + 2*j2;
    int n = tt*16 + (l&15);
    const float* src = (u<9) ? S.p[18] + (u*8)*64
                     : (u<12) ? S.p[22] + ((u-9)*8)*64
                              : S.p[26] + ((u-12)*8)*64;
    float lo = (k0   < 8) ? src[(k0  )*64 + n] : 0.f;
    float hi = (k0+1 < 8) ? src[(k0+1)*64 + n] : 0.f;
    wsU[W1F1 + i] = pk2(lo, hi);
    return;
  }
  i -= 15360;
  if (i < 7680){   // W2F1: pi2-permuted k, n>=8 -> 0
    int j2 = i & 3, l = (i>>2)&63, ks = (i>>8)&1, u = i>>9;
    int s0 = ks*32 + (l>>4)*8 + 2*j2;
    int n = l & 15;
    const float* src = (u<9) ? S.p[20] + u*512
                     : (u<12) ? S.p[24] + (u-9)*512
                              : S.p[28] + (u-12)*512;
    float lo = (n<8) ? src[pi2((s0  )&63)*8 + n] : 0.f;
    float hi = (n<8) ? src[pi2((s0+1)&63)*8 + n] : 0.f;
    wsU[W2F1 + i] = pk2(lo, hi);
    return;
  }
  i -= 7680;
  if (i < 1024){
    int u = i>>6;
    const float* src = (u<9) ? S.p[1]+u*64 : (u<12) ? S.p[5]+(u-9)*64
                     : (u<15) ? S.p[9]+(u-12)*64 : S.p[14];
    wsF[OFF_b1P0 + i] = src[i&63];
    return;
  }
  i -= 1024;
  if (i < 256){
    int u = i>>4, n = i&15;
    const float* src = (u<9) ? S.p[3]+u*8 : (u<12) ? S.p[7]+(u-9)*8
                     : (u<15) ? S.p[11]+(u-12)*8 : S.p[16];
    wsF[OFF_b2P0 + i] = (n<8) ? src[n] : 0.f;
    return;
  }
  i -= 256;
  if (i < 960){
    int u = i>>6;
    const float* src = (u<9) ? S.p[19]+u*64 : (u<12) ? S.p[23]+(u-9)*64
                               : S.p[27]+(u-12)*64;
    wsF[OFF_b1P1 + i] = src[i&63];
    return;
  }
  i -= 960;
  if (i < 240){
    int u = i>>4, n = i&15;
    const float* src = (u<9) ? S.p[21]+u*8 : (u<12) ? S.p[25]+(u-9)*8
                               : S.p[29]+(u-12)*8;
    wsF[OFF_b2P1 + i] = (n<8) ? src[n] : 0.f;
    return;
  }
  i -= 240;
  if (i < 144){ wsF[OFF_G0W3 + i] = S.p[12][i]; return; }
  i -= 144;
  if (i < 96){ wsF[OFF_SG0W3 + i] = S.p[17][i]; return; }
  i -= 96;
  if (i < 144){ wsF[OFF_G1W3 + i] = S.p[30][i]; return; }
  i -= 144;
  if (i < 24){ wsF[OFF_TW + i] = S.p[31][i]; return; }
  i -= 24;
  wsF[OFF_Tb + i] = S.p[32][i];
}

template<int N>
__device__ __forceinline__ void softmaxT(float (&v)[N]){
  float m = v[0];
  #pragma unroll
  for (int i=1;i<N;i++) m = fmaxf(m, v[i]);
  float s = 0.f;
  #pragma unroll
  for (int i=0;i<N;i++){ v[i] = __expf(v[i]-m); s += v[i]; }
  float inv = 1.f/s;
  #pragma unroll
  for (int i=0;i<N;i++) v[i] *= inv;
}

__global__ __launch_bounds__(NT, 4) void ple_kernel(
    const float* __restrict__ emb, const int* __restrict__ cat,
    const u32* __restrict__ wsU, const float* __restrict__ P,
    float* __restrict__ out, int Btot)
{
  // LDS (u32): xsA [64e][52] (x bf16 pairs, k-pad 96; pitch 52 = uniform
  // banks); aliased after phase 1 as l1in [64e][36]. obT [64e][68] (element-
  // major outputs, u16 cols u*8+n). hbW per-wave [16e][36].
  __shared__ u32 S_[9984];
  u32* xsA = S_;            // 3328
  u32* obT = S_ + 3328;     // 4352
  u32* hbW = S_ + 7680;     // 2304
  const int tid = threadIdx.x;
  const int e = tid & 63;
  const int su = __builtin_amdgcn_readfirstlane(tid >> 6);
  const int lane = tid & 63;
  const int q = lane >> 4;
  const int c16 = lane & 15;

  // ---- phase 0: gather x -> xsA [e][52], b128 writes, zero pad ----
  {
    const int eg = blockIdx.x*EPB + e;
    auto ldf = [&](int f){
      int idx = cat[eg*9 + f];
      const float* ep = emb + (long)idx*8;
      float4 a = *(const float4*)ep;
      float4 b = *(const float4*)(ep+4);
      uint4 w; w.x = pk2(a.x,a.y); w.y = pk2(a.z,a.w);
      w.z = pk2(b.x,b.y); w.w = pk2(b.z,b.w);
      *(uint4*)(xsA + e*52 + f*4) = w;
    };
    ldf(su); ldf(su+4);
    if (su == 0) ldf(8);
    *(uint4*)(xsA + e*52 + 36 + su*4) = (uint4){0,0,0,0};
  }
  __syncthreads();

  u16* obp = (u16*)obT;   // element-major: [e][136 u16], col = u*8 + n

  // ---- phase 1: level-0 MFMA, wave su owns units 4su..4su+3 ----
  {
    u32* hbU = hbW + su*576;   // [16][36] u32
    #pragma unroll 1
    for (int k4 = 0; k4 < 4; k4++){
      const int u = su*4 + k4;
      short8 bf[3][4];
      #pragma unroll
      for (int s=0;s<3;s++)
        #pragma unroll
        for (int t=0;t<4;t++)
          bf[s][t] = *(const short8*)(wsU + W1F0 + (((u*3+s)*4+t)*64 + lane)*4);
      float bias[4];
      #pragma unroll
      for (int t=0;t<4;t++) bias[t] = P[OFF_b1P0 + u*64 + t*16 + c16];
      const float ob2 = P[OFF_b2P0 + u*16 + c16];
      short8 w2f[2];
      #pragma unroll
      for (int ks=0;ks<2;ks++)
        w2f[ks] = *(const short8*)(wsU + W2F0 + ((u*2+ks)*64 + lane)*4);

      #pragma unroll 1
      for (int m=0;m<4;m++){
        short8 af[3];
        #pragma unroll
        for (int s=0;s<3;s++)
          af[s] = *(const short8*)(xsA + (m*16 + c16)*52 + s*16 + q*4);
        floatx4 acc[4];
        #pragma unroll
        for (int t=0;t<4;t++) acc[t] = (floatx4){bias[t],bias[t],bias[t],bias[t]};
        #pragma unroll
        for (int s=0;s<3;s++)
          #pragma unroll
          for (int t=0;t<4;t++)
            acc[t] = __builtin_amdgcn_mfma_f32_16x16x32_bf16(af[s], bf[s][t], acc[t], 0,0,0);
        // H relu -> pi2-packed: lane writes words 2c16,2c16+1 of row q*4+r
        #pragma unroll
        for (int r=0;r<4;r++){
          uint2 hw;
          hw.x = pk2(fmaxf(acc[0][r],0.f), fmaxf(acc[1][r],0.f));
          hw.y = pk2(fmaxf(acc[2][r],0.f), fmaxf(acc[3][r],0.f));
          *(uint2*)(hbU + (q*4+r)*36 + 2*c16) = hw;
        }
        floatx4 oc = (floatx4){ob2, ob2, ob2, ob2};
        #pragma unroll
        for (int ks=0;ks<2;ks++){
          short8 haf = *(const short8*)(hbU + c16*36 + ks*16 + q*4);
          oc = __builtin_amdgcn_mfma_f32_16x16x32_bf16(haf, w2f[ks], oc, 0,0,0);
        }
        if (c16 < 8){
          #pragma unroll
          for (int r=0;r<4;r++)
            obp[(m*16 + q*4 + r)*136 + u*8 + c16] = (u16)f2bf(fmaxf(oc[r], 0.f));
        }
      }
    }
  }
  __syncthreads();

  // ---- phase 2: level-0 gates + mixing -> l1in [64e][36] (A-frag layout) ----
  u32* l1in = xsA;   // words 0..15 data (t0,t1,t2,shared), 16..31 zero
  *(uint4*)(l1in + e*36 + 16 + su*4) = (uint4){0,0,0,0};
  if (su < 3){
    const int t = su;
    uint4 gw = *(const uint4*)(obT + e*68 + (12+t)*4);
    float g8[8] = {bflo(gw.x),bfhi(gw.x),bflo(gw.y),bfhi(gw.y),
                   bflo(gw.z),bfhi(gw.z),bflo(gw.w),bfhi(gw.w)};
    float lg[6];
    #pragma unroll
    for (int m=0;m<6;m++){
      float s = 0.f;
      #pragma unroll
      for (int j=0;j<8;j++) s = fmaf(g8[j], P[OFF_G0W3 + t*48 + j*6 + m], s);
      lg[m] = s;
    }
    softmaxT<6>(lg);
    float in8[8] = {0,0,0,0,0,0,0,0};
    #pragma unroll
    for (int x=0;x<6;x++){
      const int uu = (x<3) ? t*3+x : 9+(x-3);
      float wv = lg[x];
      uint4 ow = *(const uint4*)(obT + e*68 + uu*4);
      in8[0] = fmaf(wv, bflo(ow.x), in8[0]); in8[1] = fmaf(wv, bfhi(ow.x), in8[1]);
      in8[2] = fmaf(wv, bflo(ow.y), in8[2]); in8[3] = fmaf(wv, bfhi(ow.y), in8[3]);
      in8[4] = fmaf(wv, bflo(ow.z), in8[4]); in8[5] = fmaf(wv, bfhi(ow.z), in8[5]);
      in8[6] = fmaf(wv, bflo(ow.w), in8[6]); in8[7] = fmaf(wv, bfhi(ow.w), in8[7]);
    }
    uint4 lw4; lw4.x = pk2(in8[0],in8[1]); lw4.y = pk2(in8[2],in8[3]);
    lw4.z = pk2(in8[4],in8[5]); lw4.w = pk2(in8[6],in8[7]);
    *(uint4*)(l1in + e*36 + t*4) = lw4;
  } else {
    uint4 gw = *(const uint4*)(obT + e*68 + 15*4);
    float g8[8] = {bflo(gw.x),bfhi(gw.x),bflo(gw.y),bfhi(gw.y),
                   bflo(gw.z),bfhi(gw.z),bflo(gw.w),bfhi(gw.w)};
    float lw[12];
    #pragma unroll
    for (int m=0;m<12;m++){
      float s = 0.f;
      #pragma unroll
      for (int j=0;j<8;j++) s = fmaf(g8[j], P[OFF_SG0W3 + j*12 + m], s);
      lw[m] = s;
    }
    softmaxT<12>(lw);
    float in8[8] = {0,0,0,0,0,0,0,0};
    #pragma unroll
    for (int uu=0;uu<12;uu++){
      float wv = lw[uu];
      uint4 ow = *(const uint4*)(obT + e*68 + uu*4);
      in8[0] = fmaf(wv, bflo(ow.x), in8[0]); in8[1] = fmaf(wv, bfhi(ow.x), in8[1]);
      in8[2] = fmaf(wv, bflo(ow.y), in8[2]); in8[3] = fmaf(wv, bfhi(ow.y), in8[3]);
      in8[4] = fmaf(wv, bflo(ow.z), in8[4]); in8[5] = fmaf(wv, bfhi(ow.z), in8[5]);
      in8[6] = fmaf(wv, bflo(ow.w), in8[6]); in8[7] = fmaf(wv, bfhi(ow.w), in8[7]);
    }
    uint4 lw4; lw4.x = pk2(in8[0],in8[1]); lw4.y = pk2(in8[2],in8[3]);
    lw4.z = pk2(in8[4],in8[5]); lw4.w = pk2(in8[6],in8[7]);
    *(uint4*)(l1in + e*36 + 12) = lw4;
  }
  __syncthreads();

  // ---- phase 3: level-1 MFMA (15 units, K=8 zero-padded) ----
  {
    u32* hbU = hbW + su*576;
    #pragma unroll 1
    for (int k4=0;k4<4;k4++){
      const int u = su*4 + k4;
      if (u >= 15) break;
      const int base_u = (u<9) ? (u/3)*4 : ((u<12) ? 12 : (u-12)*4);
      const int aoff = (q==0) ? base_u : (16 + q*4);   // q>=1 -> zeros
      short8 bf1[4];
      #pragma unroll
      for (int t=0;t<4;t++)
        bf1[t] = *(const short8*)(wsU + W1F1 + ((u*4+t)*64 + lane)*4);
      float bias[4];
      #pragma unroll
      for (int t=0;t<4;t++) bias[t] = P[OFF_b1P1 + u*64 + t*16 + c16];
      const float ob2 = P[OFF_b2P1 + u*16 + c16];
      short8 w2f[2];
      #pragma unroll
      for (int ks=0;ks<2;ks++)
        w2f[ks] = *(const short8*)(wsU + W2F1 + ((u*2+ks)*64 + lane)*4);

      #pragma unroll 1
      for (int m=0;m<4;m++){
        short8 af = *(const short8*)(l1in + (m*16 + c16)*36 + aoff);
        floatx4 acc[4];
        #pragma unroll
        for (int t=0;t<4;t++) acc[t] = (floatx4){bias[t],bias[t],bias[t],bias[t]};
        #pragma unroll
        for (int t=0;t<4;t++)
          acc[t] = __builtin_amdgcn_mfma_f32_16x16x32_bf16(af, bf1[t], acc[t], 0,0,0);
        #pragma unroll
        for (int r=0;r<4;r++){
          uint2 hw;
          hw.x = pk2(fmaxf(acc[0][r],0.f), fmaxf(acc[1][r],0.f));
          hw.y = pk2(fmaxf(acc[2][r],0.f), fmaxf(acc[3][r],0.f));
          *(uint2*)(hbU + (q*4+r)*36 + 2*c16) = hw;
        }
        floatx4 oc = (floatx4){ob2, ob2, ob2, ob2};
        #pragma unroll
        for (int ks=0;ks<2;ks++){
          short8 haf = *(const short8*)(hbU + c16*36 + ks*16 + q*4);
          oc = __builtin_amdgcn_mfma_f32_16x16x32_bf16(haf, w2f[ks], oc, 0,0,0);
        }
        if (c16 < 8){
          #pragma unroll
          for (int r=0;r<4;r++)
            obp[(m*16 + q*4 + r)*136 + u*8 + c16] = (u16)f2bf(fmaxf(oc[r], 0.f));
        }
      }
    }
  }
  __syncthreads();

  // ---- phase 4: level-1 gates + mixing + towers ----
  if (su < 3){
    const int t = su;
    uint4 gw = *(const uint4*)(obT + e*68 + (12+t)*4);
    float g8[8] = {bflo(gw.x),bfhi(gw.x),bflo(gw.y),bfhi(gw.y),
                   bflo(gw.z),bfhi(gw.z),bflo(gw.w),bfhi(gw.w)};
    float lg[6];
    #pragma unroll
    for (int m=0;m<6;m++){
      float s = 0.f;
      #pragma unroll
      for (int j=0;j<8;j++) s = fmaf(g8[j], P[OFF_G1W3 + t*48 + j*6 + m], s);
      lg[m] = s;
    }
    softmaxT<6>(lg);
    float t1[8] = {0,0,0,0,0,0,0,0};
    #pragma unroll
    for (int x=0;x<6;x++){
      const int uu = (x<3) ? t*3+x : 9+(x-3);
      float wv = lg[x];
      uint4 ow = *(const uint4*)(obT + e*68 + uu*4);
      t1[0] = fmaf(wv, bflo(ow.x), t1[0]); t1[1] = fmaf(wv, bfhi(ow.x), t1[1]);
      t1[2] = fmaf(wv, bflo(ow.y), t1[2]); t1[3] = fmaf(wv, bfhi(ow.y), t1[3]);
      t1[4] = fmaf(wv, bflo(ow.z), t1[4]); t1[5] = fmaf(wv, bfhi(ow.z), t1[5]);
      t1[6] = fmaf(wv, bflo(ow.w), t1[6]); t1[7] = fmaf(wv, bfhi(ow.w), t1[7]);
    }
    float s = P[OFF_Tb + t];
    #pragma unroll
    for (int j=0;j<8;j++) s = fmaf(t1[j], P[OFF_TW + t*8 + j], s);
    out[t*Btot + blockIdx.x*EPB + e] = 1.f/(1.f + __expf(-s));
  }
}

extern "C" void kernel_launch(void* const* d_in, const int* in_sizes, int n_in,
                              void* d_out, int out_size, void* d_ws, size_t ws_size,
                              hipStream_t stream)
{
  const float* emb = (const float*)d_in[0];
  const int* cat = (const int*)d_in[34];
  float* out = (float*)d_out;
  u32* wsU = (u32*)d_ws;
  float* wsF = (float*)d_ws;
  PSrc S;
  for (int k=0;k<33;k++) S.p[k] = (const float*)d_in[k+1];
  const int B = in_sizes[34] / 9;   // 131072

  cvt_kernel<<<(CVT_TOTAL+255)/256, 256, 0, stream>>>(S, wsU, wsF);
  ple_kernel<<<B/EPB, NT, 0, stream>>>(emb, cat, wsU, wsF, out, B);
}

// Round 9
// 192.815 us; speedup vs baseline: 1.0111x; 1.0111x over previous
//
#include <hip/hip_runtime.h>

// PLELayer round-9: round-8 (f16 datapath + v_dot2 mixing) with the
// compile fix: clang's amdgcn builtins use __fp16 vectors ("h" type),
// not _Float16 — cvt_pkrtz returns v2 __fp16; fdot2/mfma_f32_*_f16 take
// __fp16 vectors. All f16 vector typedefs switched to __fp16.
//  - whole datapath f16 (mfma_f32_16x16x32_f16, same rate as bf16):
//    packs = 1x v_cvt_pkrtz_f16_f32, scalar cvt = 1x v_cvt_f16_f32.
//  - obT unit-major (u16 col = n*16+u): mixing = 6x v_dot2_f32_f16 per
//    output-dim (48 total) via one b128+one b64 read, vs 192 shl+fma.
//  - b1 biases pre-swizzled [u][c16][4t] -> one global b128 per unit.
// Structure (phases, tiling, pi2 H permutation) identical to r7.

#define NT 256
#define EPB 64

typedef unsigned short u16;
typedef unsigned int u32;
typedef __fp16 hv2 __attribute__((ext_vector_type(2)));
typedef __fp16 half8 __attribute__((ext_vector_type(8)));
typedef __attribute__((ext_vector_type(4))) float floatx4;

__device__ __forceinline__ u32 pkh2(float a, float b){
  hv2 v = __builtin_amdgcn_cvt_pkrtz(a, b);
  u32 r; __builtin_memcpy(&r, &v, 4); return r;
}
__device__ __forceinline__ u16 f2h(float a){
  __fp16 h = (__fp16)a; u16 r; __builtin_memcpy(&r, &h, 2); return r;
}
__device__ __forceinline__ float h2f(u16 v){
  __fp16 h; __builtin_memcpy(&h, &v, 2); return (float)h;
}
__device__ __forceinline__ float dot2(u32 a, u32 b, float c){
  hv2 av, bv; __builtin_memcpy(&av, &a, 4); __builtin_memcpy(&bv, &b, 4);
  return __builtin_amdgcn_fdot2(av, bv, c, false);
}

// pi2: H storage-k s -> real h (both levels): s = 4*c16 + t -> h = t*16+c16.
__device__ __forceinline__ int pi2(int s){
  return (s & 3)*16 + (s >> 2);
}

// ---- ws layout ----
#define W1F0 0          // [16u][3s][4t][64l][4]  = 49152 u32 (f16 pairs)
#define W2F0 49152      // [16u][2ks][64l][4]     =  8192
#define W1F1 57344      // [15u][4t][64l][4]      = 15360
#define W2F1 72704      // [15u][2ks][64l][4]     =  7680
#define OFF_b1P0 80384  // [16u][16c16][4t] fp32
#define OFF_b2P0 81408  // [16][16] cols 8..15 zero
#define OFF_b1P1 81664  // [15u][16c16][4t]
#define OFF_b2P1 82624  // [15][16] cols 8..15 zero
#define OFF_G0W3 82864  // [3][8][6]
#define OFF_SG0W3 83008 // [8][12]
#define OFF_G1W3 83104  // [3][8][6]
#define OFF_TW   83248  // [3][8]
#define OFF_Tb   83272  // [3]
#define CVT_TOTAL 83275

struct PSrc { const float* p[33]; };

__global__ void cvt_kernel(PSrc S, u32* __restrict__ wsU, float* __restrict__ wsF){
  int i = blockIdx.x*256 + threadIdx.x;
  if (i >= CVT_TOTAL) return;
  if (i < 49152){  // W1F0: B[k=s*32+q*8+j][h=t*16+c16], k>=72 -> 0
    int j2 = i & 3, l = (i>>2)&63, tt = (i>>8)&3;
    int rest = i >> 10; int s = rest % 3, u = rest / 3;
    int k0 = s*32 + (l>>4)*8 + 2*j2;
    int h  = tt*16 + (l&15);
    const float* src = (u<9)  ? S.p[0]  + (u*72)*64
                     : (u<12) ? S.p[4]  + ((u-9)*72)*64
                     : (u<15) ? S.p[8]  + ((u-12)*72)*64
                              : S.p[13];
    float lo = (k0   < 72) ? src[(k0  )*64 + h] : 0.f;
    float hi = (k0+1 < 72) ? src[(k0+1)*64 + h] : 0.f;
    wsU[i] = pkh2(lo, hi);
    return;
  }
  i -= 49152;
  if (i < 8192){   // W2F0: pi2-permuted k, n>=8 -> 0
    int j2 = i & 3, l = (i>>2)&63, ks = (i>>8)&1, u = i>>9;
    int s0 = ks*32 + (l>>4)*8 + 2*j2;
    int n = l & 15;
    const float* src = (u<9)  ? S.p[2]  + u*512
                     : (u<12) ? S.p[6]  + (u-9)*512
                     : (u<15) ? S.p[10] + (u-12)*512
                              : S.p[15];
    float lo = (n<8) ? src[pi2((s0  )&63)*8 + n] : 0.f;
    float hi = (n<8) ? src[pi2((s0+1)&63)*8 + n] : 0.f;
    wsU[W2F0 + i] = pkh2(lo, hi);
    return;
  }
  i -= 8192;
  if (i < 15360){  // W1F1: B[k=q*8+j][n=t*16+c16], k>=8 -> 0
    int j2 = i & 3, l = (i>>2)&63, tt = (i>>8)&3, u = i>>10;
    int k0 = (l>>4)*8 + 2*j2;
    int n = tt*16 + (l&15);
    const float* src = (u<9) ? S.p[18] + (u*8)*64
                     : (u<12) ? S.p[22] + ((u-9)*8)*64
                              : S.p[26] + ((u-12)*8)*64;
    float lo = (k0   < 8) ? src[(k0  )*64 + n] : 0.f;
    float hi = (k0+1 < 8) ? src[(k0+1)*64 + n] : 0.f;
    wsU[W1F1 + i] = pkh2(lo, hi);
    return;
  }
  i -= 15360;
  if (i < 7680){   // W2F1: pi2-permuted k, n>=8 -> 0
    int j2 = i & 3, l = (i>>2)&63, ks = (i>>8)&1, u = i>>9;
    int s0 = ks*32 + (l>>4)*8 + 2*j2;
    int n = l & 15;
    const float* src = (u<9) ? S.p[20] + u*512
                     : (u<12) ? S.p[24] + (u-9)*512
                              : S.p[28] + (u-12)*512;
    float lo = (n<8) ? src[pi2((s0  )&63)*8 + n] : 0.f;
    float hi = (n<8) ? src[pi2((s0+1)&63)*8 + n] : 0.f;
    wsU[W2F1 + i] = pkh2(lo, hi);
    return;
  }
  i -= 7680;
  if (i < 1024){   // b1P0 swizzled [u][c16][t]
    int u = i>>6, r = i&63, c16 = r>>2, t = r&3;
    const float* src = (u<9) ? S.p[1]+u*64 : (u<12) ? S.p[5]+(u-9)*64
                     : (u<15) ? S.p[9]+(u-12)*64 : S.p[14];
    wsF[OFF_b1P0 + i] = src[t*16 + c16];
    return;
  }
  i -= 1024;
  if (i < 256){
    int u = i>>4, n = i&15;
    const float* src = (u<9) ? S.p[3]+u*8 : (u<12) ? S.p[7]+(u-9)*8
                     : (u<15) ? S.p[11]+(u-12)*8 : S.p[16];
    wsF[OFF_b2P0 + i] = (n<8) ? src[n] : 0.f;
    return;
  }
  i -= 256;
  if (i < 960){    // b1P1 swizzled [u][c16][t]
    int u = i>>6, r = i&63, c16 = r>>2, t = r&3;
    const float* src = (u<9) ? S.p[19]+u*64 : (u<12) ? S.p[23]+(u-9)*64
                               : S.p[27]+(u-12)*64;
    wsF[OFF_b1P1 + i] = src[t*16 + c16];
    return;
  }
  i -= 960;
  if (i < 240){
    int u = i>>4, n = i&15;
    const float* src = (u<9) ? S.p[21]+u*8 : (u<12) ? S.p[25]+(u-9)*8
                               : S.p[29]+(u-12)*8;
    wsF[OFF_b2P1 + i] = (n<8) ? src[n] : 0.f;
    return;
  }
  i -= 240;
  if (i < 144){ wsF[OFF_G0W3 + i] = S.p[12][i]; return; }
  i -= 144;
  if (i < 96){ wsF[OFF_SG0W3 + i] = S.p[17][i]; return; }
  i -= 96;
  if (i < 144){ wsF[OFF_G1W3 + i] = S.p[30][i]; return; }
  i -= 144;
  if (i < 24){ wsF[OFF_TW + i] = S.p[31][i]; return; }
  i -= 24;
  wsF[OFF_Tb + i] = S.p[32][i];
}

template<int N>
__device__ __forceinline__ void softmaxT(float (&v)[N]){
  float m = v[0];
  #pragma unroll
  for (int i=1;i<N;i++) m = fmaxf(m, v[i]);
  float s = 0.f;
  #pragma unroll
  for (int i=0;i<N;i++){ v[i] = __expf(v[i]-m); s += v[i]; }
  float inv = 1.f/s;
  #pragma unroll
  for (int i=0;i<N;i++) v[i] *= inv;
}

__global__ __launch_bounds__(NT, 4) void ple_kernel(
    const float* __restrict__ emb, const int* __restrict__ cat,
    const u32* __restrict__ wsU, const float* __restrict__ P,
    float* __restrict__ out, int Btot)
{
  // LDS (u32): xsA [64e][52] (x f16 pairs, k-pad 96); aliased after phase 1
  // as l1in [64e][36]. obT [64e][68]: u16 col = n*16 + u (unit-major pairs).
  // hbW per-wave [16e][36].
  __shared__ u32 S_[9984];
  u32* xsA = S_;            // 3328
  u32* obT = S_ + 3328;     // 4352
  u32* hbW = S_ + 7680;     // 2304
  const int tid = threadIdx.x;
  const int e = tid & 63;
  const int su = __builtin_amdgcn_readfirstlane(tid >> 6);
  const int lane = tid & 63;
  const int q = lane >> 4;
  const int c16 = lane & 15;

  // ---- phase 0: gather x -> xsA [e][52] f16 pairs, zero pad ----
  {
    const int eg = blockIdx.x*EPB + e;
    auto ldf = [&](int f){
      int idx = cat[eg*9 + f];
      const float* ep = emb + (long)idx*8;
      float4 a = *(const float4*)ep;
      float4 b = *(const float4*)(ep+4);
      uint4 w; w.x = pkh2(a.x,a.y); w.y = pkh2(a.z,a.w);
      w.z = pkh2(b.x,b.y); w.w = pkh2(b.z,b.w);
      *(uint4*)(xsA + e*52 + f*4) = w;
    };
    ldf(su); ldf(su+4);
    if (su == 0) ldf(8);
    *(uint4*)(xsA + e*52 + 36 + su*4) = (uint4){0,0,0,0};
  }
  __syncthreads();

  u16* obp = (u16*)obT;   // [e][136 u16], col = n*16 + u

  // ---- phase 1: level-0 MFMA (f16), wave su owns units 4su..4su+3 ----
  {
    u32* hbU = hbW + su*576;   // [16][36] u32
    #pragma unroll 1
    for (int k4 = 0; k4 < 4; k4++){
      const int u = su*4 + k4;
      half8 bf[3][4];
      #pragma unroll
      for (int s=0;s<3;s++)
        #pragma unroll
        for (int t=0;t<4;t++)
          bf[s][t] = *(const half8*)(wsU + W1F0 + (((u*3+s)*4+t)*64 + lane)*4);
      float4 bias4 = *(const float4*)(P + OFF_b1P0 + u*64 + c16*4);
      float bias[4] = {bias4.x, bias4.y, bias4.z, bias4.w};
      const float ob2 = P[OFF_b2P0 + u*16 + c16];
      half8 w2f[2];
      #pragma unroll
      for (int ks=0;ks<2;ks++)
        w2f[ks] = *(const half8*)(wsU + W2F0 + ((u*2+ks)*64 + lane)*4);

      #pragma unroll 1
      for (int m=0;m<4;m++){
        half8 af[3];
        #pragma unroll
        for (int s=0;s<3;s++)
          af[s] = *(const half8*)(xsA + (m*16 + c16)*52 + s*16 + q*4);
        floatx4 acc[4];
        #pragma unroll
        for (int t=0;t<4;t++) acc[t] = (floatx4){bias[t],bias[t],bias[t],bias[t]};
        #pragma unroll
        for (int s=0;s<3;s++)
          #pragma unroll
          for (int t=0;t<4;t++)
            acc[t] = __builtin_amdgcn_mfma_f32_16x16x32_f16(af[s], bf[s][t], acc[t], 0,0,0);
        // H relu -> pi2-packed f16 pairs
        #pragma unroll
        for (int r=0;r<4;r++){
          uint2 hw;
          hw.x = pkh2(fmaxf(acc[0][r],0.f), fmaxf(acc[1][r],0.f));
          hw.y = pkh2(fmaxf(acc[2][r],0.f), fmaxf(acc[3][r],0.f));
          *(uint2*)(hbU + (q*4+r)*36 + 2*c16) = hw;
        }
        floatx4 oc = (floatx4){ob2, ob2, ob2, ob2};
        #pragma unroll
        for (int ks=0;ks<2;ks++){
          half8 haf = *(const half8*)(hbU + c16*36 + ks*16 + q*4);
          oc = __builtin_amdgcn_mfma_f32_16x16x32_f16(haf, w2f[ks], oc, 0,0,0);
        }
        if (c16 < 8){
          #pragma unroll
          for (int r=0;r<4;r++)
            obp[(m*16 + q*4 + r)*136 + c16*16 + u] = f2h(fmaxf(oc[r], 0.f));
        }
      }
    }
  }
  __syncthreads();

  // ---- phase 2: level-0 gates + dot2 mixing -> l1in [64e][36] ----
  u32* l1in = xsA;
  *(uint4*)(l1in + e*36 + 16 + su*4) = (uint4){0,0,0,0};
  {
    float wv12[12];
    {
      const int ug = (su<3) ? 12+su : 15;
      float g8[8];
      #pragma unroll
      for (int j=0;j<8;j++) g8[j] = h2f(obp[e*136 + j*16 + ug]);
      if (su < 3){
        const int t = su;
        float lg[6];
        #pragma unroll
        for (int m=0;m<6;m++){
          float s = 0.f;
          #pragma unroll
          for (int j=0;j<8;j++) s = fmaf(g8[j], P[OFF_G0W3 + t*48 + j*6 + m], s);
          lg[m] = s;
        }
        softmaxT<6>(lg);
        #pragma unroll
        for (int k=0;k<12;k++) wv12[k] = 0.f;
        #pragma unroll
        for (int x=0;x<3;x++) wv12[t*3+x] = lg[x];
        #pragma unroll
        for (int s3=0;s3<3;s3++) wv12[9+s3] = lg[3+s3];
      } else {
        float lw[12];
        #pragma unroll
        for (int m=0;m<12;m++){
          float s = 0.f;
          #pragma unroll
          for (int j=0;j<8;j++) s = fmaf(g8[j], P[OFF_SG0W3 + j*12 + m], s);
          lw[m] = s;
        }
        softmaxT<12>(lw);
        #pragma unroll
        for (int k=0;k<12;k++) wv12[k] = lw[k];
      }
    }
    u32 wp[6];
    #pragma unroll
    for (int p=0;p<6;p++) wp[p] = pkh2(wv12[2*p], wv12[2*p+1]);
    float in8[8];
    #pragma unroll
    for (int n=0;n<8;n++){
      const u32* rowp = obT + e*68 + n*8;
      uint4 A = *(const uint4*)rowp;
      uint2 Bv = *(const uint2*)(rowp + 4);
      float s = dot2(A.x, wp[0], 0.f);
      s = dot2(A.y, wp[1], s);
      s = dot2(A.z, wp[2], s);
      s = dot2(A.w, wp[3], s);
      s = dot2(Bv.x, wp[4], s);
      s = dot2(Bv.y, wp[5], s);
      in8[n] = s;
    }
    const int dst = (su<3) ? su*4 : 12;
    uint4 lw4; lw4.x = pkh2(in8[0],in8[1]); lw4.y = pkh2(in8[2],in8[3]);
    lw4.z = pkh2(in8[4],in8[5]); lw4.w = pkh2(in8[6],in8[7]);
    *(uint4*)(l1in + e*36 + dst) = lw4;
  }
  __syncthreads();

  // ---- phase 3: level-1 MFMA (15 units, K=8 zero-padded) ----
  {
    u32* hbU = hbW + su*576;
    #pragma unroll 1
    for (int k4=0;k4<4;k4++){
      const int u = su*4 + k4;
      if (u >= 15) break;
      const int base_u = (u<9) ? (u/3)*4 : ((u<12) ? 12 : (u-12)*4);
      const int aoff = (q==0) ? base_u : (16 + q*4);   // q>=1 -> zeros
      half8 bf1[4];
      #pragma unroll
      for (int t=0;t<4;t++)
        bf1[t] = *(const half8*)(wsU + W1F1 + ((u*4+t)*64 + lane)*4);
      float4 bias4 = *(const float4*)(P + OFF_b1P1 + u*64 + c16*4);
      float bias[4] = {bias4.x, bias4.y, bias4.z, bias4.w};
      const float ob2 = P[OFF_b2P1 + u*16 + c16];
      half8 w2f[2];
      #pragma unroll
      for (int ks=0;ks<2;ks++)
        w2f[ks] = *(const half8*)(wsU + W2F1 + ((u*2+ks)*64 + lane)*4);

      #pragma unroll 1
      for (int m=0;m<4;m++){
        half8 af = *(const half8*)(l1in + (m*16 + c16)*36 + aoff);
        floatx4 acc[4];
        #pragma unroll
        for (int t=0;t<4;t++) acc[t] = (floatx4){bias[t],bias[t],bias[t],bias[t]};
        #pragma unroll
        for (int t=0;t<4;t++)
          acc[t] = __builtin_amdgcn_mfma_f32_16x16x32_f16(af, bf1[t], acc[t], 0,0,0);
        #pragma unroll
        for (int r=0;r<4;r++){
          uint2 hw;
          hw.x = pkh2(fmaxf(acc[0][r],0.f), fmaxf(acc[1][r],0.f));
          hw.y = pkh2(fmaxf(acc[2][r],0.f), fmaxf(acc[3][r],0.f));
          *(uint2*)(hbU + (q*4+r)*36 + 2*c16) = hw;
        }
        floatx4 oc = (floatx4){ob2, ob2, ob2, ob2};
        #pragma unroll
        for (int ks=0;ks<2;ks++){
          half8 haf = *(const half8*)(hbU + c16*36 + ks*16 + q*4);
          oc = __builtin_amdgcn_mfma_f32_16x16x32_f16(haf, w2f[ks], oc, 0,0,0);
        }
        if (c16 < 8){
          #pragma unroll
          for (int r=0;r<4;r++)
            obp[(m*16 + q*4 + r)*136 + c16*16 + u] = f2h(fmaxf(oc[r], 0.f));
        }
      }
    }
  }
  __syncthreads();

  // ---- phase 4: level-1 gates + dot2 mixing + towers ----
  if (su < 3){
    const int t = su;
    float g8[8];
    #pragma unroll
    for (int j=0;j<8;j++) g8[j] = h2f(obp[e*136 + j*16 + 12+t]);
    float lg[6];
    #pragma unroll
    for (int m=0;m<6;m++){
      float s = 0.f;
      #pragma unroll
      for (int j=0;j<8;j++) s = fmaf(g8[j], P[OFF_G1W3 + t*48 + j*6 + m], s);
      lg[m] = s;
    }
    softmaxT<6>(lg);
    float wv12[12];
    #pragma unroll
    for (int k=0;k<12;k++) wv12[k] = 0.f;
    #pragma unroll
    for (int x=0;x<3;x++) wv12[t*3+x] = lg[x];
    #pragma unroll
    for (int s3=0;s3<3;s3++) wv12[9+s3] = lg[3+s3];
    u32 wp[6];
    #pragma unroll
    for (int p=0;p<6;p++) wp[p] = pkh2(wv12[2*p], wv12[2*p+1]);
    float s = P[OFF_Tb + t];
    #pragma unroll
    for (int n=0;n<8;n++){
      const u32* rowp = obT + e*68 + n*8;
      uint4 A = *(const uint4*)rowp;
      uint2 Bv = *(const uint2*)(rowp + 4);
      float v = dot2(A.x, wp[0], 0.f);
      v = dot2(A.y, wp[1], v);
      v = dot2(A.z, wp[2], v);
      v = dot2(A.w, wp[3], v);
      v = dot2(Bv.x, wp[4], v);
      v = dot2(Bv.y, wp[5], v);
      s = fmaf(v, P[OFF_TW + t*8 + n], s);
    }
    out[t*Btot + blockIdx.x*EPB + e] = 1.f/(1.f + __expf(-s));
  }
}

extern "C" void kernel_launch(void* const* d_in, const int* in_sizes, int n_in,
                              void* d_out, int out_size, void* d_ws, size_t ws_size,
                              hipStream_t stream)
{
  const float* emb = (const float*)d_in[0];
  const int* cat = (const int*)d_in[34];
  float* out = (float*)d_out;
  u32* wsU = (u32*)d_ws;
  float* wsF = (float*)d_ws;
  PSrc S;
  for (int k=0;k<33;k++) S.p[k] = (const float*)d_in[k+1];
  const int B = in_sizes[34] / 9;   // 131072

  cvt_kernel<<<(CVT_TOTAL+255)/256, 256, 0, stream>>>(S, wsU, wsF);
  ple_kernel<<<B/EPB, NT, 0, stream>>>(emb, cat, wsU, wsF, out, B);
}

// Round 10
// 189.412 us; speedup vs baseline: 1.0292x; 1.0180x over previous
//
#include <hip/hip_runtime.h>

// PLELayer round-10: fix r9's two counter-exposed regressions.
// (a) scratch spill (WRITE_SIZE 31MB): wv12[t*3+x] with runtime t demoted
//     the array to scratch. Rebuilt with compile-time indices only.
// (b) 8-way bank conflict on O-stores (11.3M cycles): obT rows get a
//     row-dependent shift of 4*((row>>2)&1) words (= 4*(q&1) at store,
//     lane-constant). Uniform shift keeps rows bijective + uint4 reads
//     16B-aligned; store banks spread 4->8 distinct (8-way -> 4-way).
// Everything else identical to r9 (f16 MFMA datapath, dot2 mixing,
// pi2 H permutation, pitch-52 xsA, pitch-68 obT).

#define NT 256
#define EPB 64

typedef unsigned short u16;
typedef unsigned int u32;
typedef __fp16 hv2 __attribute__((ext_vector_type(2)));
typedef __fp16 half8 __attribute__((ext_vector_type(8)));
typedef __attribute__((ext_vector_type(4))) float floatx4;

__device__ __forceinline__ u32 pkh2(float a, float b){
  hv2 v = __builtin_amdgcn_cvt_pkrtz(a, b);
  u32 r; __builtin_memcpy(&r, &v, 4); return r;
}
__device__ __forceinline__ u16 f2h(float a){
  __fp16 h = (__fp16)a; u16 r; __builtin_memcpy(&r, &h, 2); return r;
}
__device__ __forceinline__ float h2f(u16 v){
  __fp16 h; __builtin_memcpy(&h, &v, 2); return (float)h;
}
__device__ __forceinline__ float dot2(u32 a, u32 b, float c){
  hv2 av, bv; __builtin_memcpy(&av, &a, 4); __builtin_memcpy(&bv, &b, 4);
  return __builtin_amdgcn_fdot2(av, bv, c, false);
}

// pi2: H storage-k s -> real h (both levels): s = 4*c16 + t -> h = t*16+c16.
__device__ __forceinline__ int pi2(int s){
  return (s & 3)*16 + (s >> 2);
}

// ---- ws layout ----
#define W1F0 0          // [16u][3s][4t][64l][4]  = 49152 u32 (f16 pairs)
#define W2F0 49152      // [16u][2ks][64l][4]     =  8192
#define W1F1 57344      // [15u][4t][64l][4]      = 15360
#define W2F1 72704      // [15u][2ks][64l][4]     =  7680
#define OFF_b1P0 80384  // [16u][16c16][4t] fp32
#define OFF_b2P0 81408  // [16][16] cols 8..15 zero
#define OFF_b1P1 81664  // [15u][16c16][4t]
#define OFF_b2P1 82624  // [15][16] cols 8..15 zero
#define OFF_G0W3 82864  // [3][8][6]
#define OFF_SG0W3 83008 // [8][12]
#define OFF_G1W3 83104  // [3][8][6]
#define OFF_TW   83248  // [3][8]
#define OFF_Tb   83272  // [3]
#define CVT_TOTAL 83275

struct PSrc { const float* p[33]; };

__global__ void cvt_kernel(PSrc S, u32* __restrict__ wsU, float* __restrict__ wsF){
  int i = blockIdx.x*256 + threadIdx.x;
  if (i >= CVT_TOTAL) return;
  if (i < 49152){  // W1F0: B[k=s*32+q*8+j][h=t*16+c16], k>=72 -> 0
    int j2 = i & 3, l = (i>>2)&63, tt = (i>>8)&3;
    int rest = i >> 10; int s = rest % 3, u = rest / 3;
    int k0 = s*32 + (l>>4)*8 + 2*j2;
    int h  = tt*16 + (l&15);
    const float* src = (u<9)  ? S.p[0]  + (u*72)*64
                     : (u<12) ? S.p[4]  + ((u-9)*72)*64
                     : (u<15) ? S.p[8]  + ((u-12)*72)*64
                              : S.p[13];
    float lo = (k0   < 72) ? src[(k0  )*64 + h] : 0.f;
    float hi = (k0+1 < 72) ? src[(k0+1)*64 + h] : 0.f;
    wsU[i] = pkh2(lo, hi);
    return;
  }
  i -= 49152;
  if (i < 8192){   // W2F0: pi2-permuted k, n>=8 -> 0
    int j2 = i & 3, l = (i>>2)&63, ks = (i>>8)&1, u = i>>9;
    int s0 = ks*32 + (l>>4)*8 + 2*j2;
    int n = l & 15;
    const float* src = (u<9)  ? S.p[2]  + u*512
                     : (u<12) ? S.p[6]  + (u-9)*512
                     : (u<15) ? S.p[10] + (u-12)*512
                              : S.p[15];
    float lo = (n<8) ? src[pi2((s0  )&63)*8 + n] : 0.f;
    float hi = (n<8) ? src[pi2((s0+1)&63)*8 + n] : 0.f;
    wsU[W2F0 + i] = pkh2(lo, hi);
    return;
  }
  i -= 8192;
  if (i < 15360){  // W1F1: B[k=q*8+j][n=t*16+c16], k>=8 -> 0
    int j2 = i & 3, l = (i>>2)&63, tt = (i>>8)&3, u = i>>10;
    int k0 = (l>>4)*8 + 2*j2;
    int n = tt*16 + (l&15);
    const float* src = (u<9) ? S.p[18] + (u*8)*64
                     : (u<12) ? S.p[22] + ((u-9)*8)*64
                              : S.p[26] + ((u-12)*8)*64;
    float lo = (k0   < 8) ? src[(k0  )*64 + n] : 0.f;
    float hi = (k0+1 < 8) ? src[(k0+1)*64 + n] : 0.f;
    wsU[W1F1 + i] = pkh2(lo, hi);
    return;
  }
  i -= 15360;
  if (i < 7680){   // W2F1: pi2-permuted k, n>=8 -> 0
    int j2 = i & 3, l = (i>>2)&63, ks = (i>>8)&1, u = i>>9;
    int s0 = ks*32 + (l>>4)*8 + 2*j2;
    int n = l & 15;
    const float* src = (u<9) ? S.p[20] + u*512
                     : (u<12) ? S.p[24] + (u-9)*512
                              : S.p[28] + (u-12)*512;
    float lo = (n<8) ? src[pi2((s0  )&63)*8 + n] : 0.f;
    float hi = (n<8) ? src[pi2((s0+1)&63)*8 + n] : 0.f;
    wsU[W2F1 + i] = pkh2(lo, hi);
    return;
  }
  i -= 7680;
  if (i < 1024){   // b1P0 swizzled [u][c16][t]
    int u = i>>6, r = i&63, c16 = r>>2, t = r&3;
    const float* src = (u<9) ? S.p[1]+u*64 : (u<12) ? S.p[5]+(u-9)*64
                     : (u<15) ? S.p[9]+(u-12)*64 : S.p[14];
    wsF[OFF_b1P0 + i] = src[t*16 + c16];
    return;
  }
  i -= 1024;
  if (i < 256){
    int u = i>>4, n = i&15;
    const float* src = (u<9) ? S.p[3]+u*8 : (u<12) ? S.p[7]+(u-9)*8
                     : (u<15) ? S.p[11]+(u-12)*8 : S.p[16];
    wsF[OFF_b2P0 + i] = (n<8) ? src[n] : 0.f;
    return;
  }
  i -= 256;
  if (i < 960){    // b1P1 swizzled [u][c16][t]
    int u = i>>6, r = i&63, c16 = r>>2, t = r&3;
    const float* src = (u<9) ? S.p[19]+u*64 : (u<12) ? S.p[23]+(u-9)*64
                               : S.p[27]+(u-12)*64;
    wsF[OFF_b1P1 + i] = src[t*16 + c16];
    return;
  }
  i -= 960;
  if (i < 240){
    int u = i>>4, n = i&15;
    const float* src = (u<9) ? S.p[21]+u*8 : (u<12) ? S.p[25]+(u-9)*8
                               : S.p[29]+(u-12)*8;
    wsF[OFF_b2P1 + i] = (n<8) ? src[n] : 0.f;
    return;
  }
  i -= 240;
  if (i < 144){ wsF[OFF_G0W3 + i] = S.p[12][i]; return; }
  i -= 144;
  if (i < 96){ wsF[OFF_SG0W3 + i] = S.p[17][i]; return; }
  i -= 96;
  if (i < 144){ wsF[OFF_G1W3 + i] = S.p[30][i]; return; }
  i -= 144;
  if (i < 24){ wsF[OFF_TW + i] = S.p[31][i]; return; }
  i -= 24;
  wsF[OFF_Tb + i] = S.p[32][i];
}

template<int N>
__device__ __forceinline__ void softmaxT(float (&v)[N]){
  float m = v[0];
  #pragma unroll
  for (int i=1;i<N;i++) m = fmaxf(m, v[i]);
  float s = 0.f;
  #pragma unroll
  for (int i=0;i<N;i++){ v[i] = __expf(v[i]-m); s += v[i]; }
  float inv = 1.f/s;
  #pragma unroll
  for (int i=0;i<N;i++) v[i] *= inv;
}

__global__ __launch_bounds__(NT, 4) void ple_kernel(
    const float* __restrict__ emb, const int* __restrict__ cat,
    const u32* __restrict__ wsU, const float* __restrict__ P,
    float* __restrict__ out, int Btot)
{
  // LDS (u32): xsA [64e][52]; aliased as l1in [64e][36] after phase 1.
  // obT [64e][68]: per-row content shifted by shw(row)=4*((row>>2)&1) words.
  // hbW per-wave [16e][36].
  __shared__ u32 S_[9984];
  u32* xsA = S_;            // 3328
  u32* obT = S_ + 3328;     // 4352
  u32* hbW = S_ + 7680;     // 2304
  const int tid = threadIdx.x;
  const int e = tid & 63;
  const int su = __builtin_amdgcn_readfirstlane(tid >> 6);
  const int lane = tid & 63;
  const int q = lane >> 4;
  const int c16 = lane & 15;
  const int shw_e = ((e>>2)&1)*4;      // row shift for element-row reads (words)

  // ---- phase 0: gather x -> xsA [e][52] f16 pairs, zero pad ----
  {
    const int eg = blockIdx.x*EPB + e;
    auto ldf = [&](int f){
      int idx = cat[eg*9 + f];
      const float* ep = emb + (long)idx*8;
      float4 a = *(const float4*)ep;
      float4 b = *(const float4*)(ep+4);
      uint4 w; w.x = pkh2(a.x,a.y); w.y = pkh2(a.z,a.w);
      w.z = pkh2(b.x,b.y); w.w = pkh2(b.z,b.w);
      *(uint4*)(xsA + e*52 + f*4) = w;
    };
    ldf(su); ldf(su+4);
    if (su == 0) ldf(8);
    *(uint4*)(xsA + e*52 + 36 + su*4) = (uint4){0,0,0,0};
  }
  __syncthreads();

  u16* obp = (u16*)obT;                 // [e][136 u16]
  const int sh16_q = ((q&1) ? 8 : 0);   // store-side row shift in u16 units

  // ---- phase 1: level-0 MFMA (f16), wave su owns units 4su..4su+3 ----
  {
    u32* hbU = hbW + su*576;   // [16][36] u32
    #pragma unroll 1
    for (int k4 = 0; k4 < 4; k4++){
      const int u = su*4 + k4;
      half8 bf[3][4];
      #pragma unroll
      for (int s=0;s<3;s++)
        #pragma unroll
        for (int t=0;t<4;t++)
          bf[s][t] = *(const half8*)(wsU + W1F0 + (((u*3+s)*4+t)*64 + lane)*4);
      float4 bias4 = *(const float4*)(P + OFF_b1P0 + u*64 + c16*4);
      float bias[4] = {bias4.x, bias4.y, bias4.z, bias4.w};
      const float ob2 = P[OFF_b2P0 + u*16 + c16];
      half8 w2f[2];
      #pragma unroll
      for (int ks=0;ks<2;ks++)
        w2f[ks] = *(const half8*)(wsU + W2F0 + ((u*2+ks)*64 + lane)*4);

      #pragma unroll 1
      for (int m=0;m<4;m++){
        half8 af[3];
        #pragma unroll
        for (int s=0;s<3;s++)
          af[s] = *(const half8*)(xsA + (m*16 + c16)*52 + s*16 + q*4);
        floatx4 acc[4];
        #pragma unroll
        for (int t=0;t<4;t++) acc[t] = (floatx4){bias[t],bias[t],bias[t],bias[t]};
        #pragma unroll
        for (int s=0;s<3;s++)
          #pragma unroll
          for (int t=0;t<4;t++)
            acc[t] = __builtin_amdgcn_mfma_f32_16x16x32_f16(af[s], bf[s][t], acc[t], 0,0,0);
        // H relu -> pi2-packed f16 pairs
        #pragma unroll
        for (int r=0;r<4;r++){
          uint2 hw;
          hw.x = pkh2(fmaxf(acc[0][r],0.f), fmaxf(acc[1][r],0.f));
          hw.y = pkh2(fmaxf(acc[2][r],0.f), fmaxf(acc[3][r],0.f));
          *(uint2*)(hbU + (q*4+r)*36 + 2*c16) = hw;
        }
        floatx4 oc = (floatx4){ob2, ob2, ob2, ob2};
        #pragma unroll
        for (int ks=0;ks<2;ks++){
          half8 haf = *(const half8*)(hbU + c16*36 + ks*16 + q*4);
          oc = __builtin_amdgcn_mfma_f32_16x16x32_f16(haf, w2f[ks], oc, 0,0,0);
        }
        if (c16 < 8){
          #pragma unroll
          for (int r=0;r<4;r++)
            obp[(m*16 + q*4 + r)*136 + sh16_q + c16*16 + u] = f2h(fmaxf(oc[r], 0.f));
        }
      }
    }
  }
  __syncthreads();

  // ---- phase 2: level-0 gates + dot2 mixing -> l1in [64e][36] ----
  u32* l1in = xsA;
  *(uint4*)(l1in + e*36 + 16 + su*4) = (uint4){0,0,0,0};
  {
    float wv[12];   // static-index only (scratch-spill fix)
    {
      const int ug = (su<3) ? 12+su : 15;
      float g8[8];
      #pragma unroll
      for (int j=0;j<8;j++) g8[j] = h2f(obp[e*136 + 2*shw_e + j*16 + ug]);
      if (su < 3){
        float lg[6];
        #pragma unroll
        for (int m=0;m<6;m++){
          float s = 0.f;
          #pragma unroll
          for (int j=0;j<8;j++) s = fmaf(g8[j], P[OFF_G0W3 + su*48 + j*6 + m], s);
          lg[m] = s;
        }
        softmaxT<6>(lg);
        #pragma unroll
        for (int k=0;k<12;k++)
          wv[k] = (k<9) ? (((k/3)==su) ? lg[k%3] : 0.f) : lg[k-6];
      } else {
        float lw[12];
        #pragma unroll
        for (int m=0;m<12;m++){
          float s = 0.f;
          #pragma unroll
          for (int j=0;j<8;j++) s = fmaf(g8[j], P[OFF_SG0W3 + j*12 + m], s);
          lw[m] = s;
        }
        softmaxT<12>(lw);
        #pragma unroll
        for (int k=0;k<12;k++) wv[k] = lw[k];
      }
    }
    u32 wp[6];
    #pragma unroll
    for (int p=0;p<6;p++) wp[p] = pkh2(wv[2*p], wv[2*p+1]);
    float in8[8];
    #pragma unroll
    for (int n=0;n<8;n++){
      const u32* rowp = obT + e*68 + shw_e + n*8;
      uint4 A = *(const uint4*)rowp;
      uint2 Bv = *(const uint2*)(rowp + 4);
      float s = dot2(A.x, wp[0], 0.f);
      s = dot2(A.y, wp[1], s);
      s = dot2(A.z, wp[2], s);
      s = dot2(A.w, wp[3], s);
      s = dot2(Bv.x, wp[4], s);
      s = dot2(Bv.y, wp[5], s);
      in8[n] = s;
    }
    const int dst = (su<3) ? su*4 : 12;
    uint4 lw4; lw4.x = pkh2(in8[0],in8[1]); lw4.y = pkh2(in8[2],in8[3]);
    lw4.z = pkh2(in8[4],in8[5]); lw4.w = pkh2(in8[6],in8[7]);
    *(uint4*)(l1in + e*36 + dst) = lw4;
  }
  __syncthreads();

  // ---- phase 3: level-1 MFMA (15 units, K=8 zero-padded) ----
  {
    u32* hbU = hbW + su*576;
    #pragma unroll 1
    for (int k4=0;k4<4;k4++){
      const int u = su*4 + k4;
      if (u >= 15) break;
      const int base_u = (u<9) ? (u/3)*4 : ((u<12) ? 12 : (u-12)*4);
      const int aoff = (q==0) ? base_u : (16 + q*4);   // q>=1 -> zeros
      half8 bf1[4];
      #pragma unroll
      for (int t=0;t<4;t++)
        bf1[t] = *(const half8*)(wsU + W1F1 + ((u*4+t)*64 + lane)*4);
      float4 bias4 = *(const float4*)(P + OFF_b1P1 + u*64 + c16*4);
      float bias[4] = {bias4.x, bias4.y, bias4.z, bias4.w};
      const float ob2 = P[OFF_b2P1 + u*16 + c16];
      half8 w2f[2];
      #pragma unroll
      for (int ks=0;ks<2;ks++)
        w2f[ks] = *(const half8*)(wsU + W2F1 + ((u*2+ks)*64 + lane)*4);

      #pragma unroll 1
      for (int m=0;m<4;m++){
        half8 af = *(const half8*)(l1in + (m*16 + c16)*36 + aoff);
        floatx4 acc[4];
        #pragma unroll
        for (int t=0;t<4;t++) acc[t] = (floatx4){bias[t],bias[t],bias[t],bias[t]};
        #pragma unroll
        for (int t=0;t<4;t++)
          acc[t] = __builtin_amdgcn_mfma_f32_16x16x32_f16(af, bf1[t], acc[t], 0,0,0);
        #pragma unroll
        for (int r=0;r<4;r++){
          uint2 hw;
          hw.x = pkh2(fmaxf(acc[0][r],0.f), fmaxf(acc[1][r],0.f));
          hw.y = pkh2(fmaxf(acc[2][r],0.f), fmaxf(acc[3][r],0.f));
          *(uint2*)(hbU + (q*4+r)*36 + 2*c16) = hw;
        }
        floatx4 oc = (floatx4){ob2, ob2, ob2, ob2};
        #pragma unroll
        for (int ks=0;ks<2;ks++){
          half8 haf = *(const half8*)(hbU + c16*36 + ks*16 + q*4);
          oc = __builtin_amdgcn_mfma_f32_16x16x32_f16(haf, w2f[ks], oc, 0,0,0);
        }
        if (c16 < 8){
          #pragma unroll
          for (int r=0;r<4;r++)
            obp[(m*16 + q*4 + r)*136 + sh16_q + c16*16 + u] = f2h(fmaxf(oc[r], 0.f));
        }
      }
    }
  }
  __syncthreads();

  // ---- phase 4: level-1 gates + dot2 mixing + towers ----
  if (su < 3){
    const int t = su;
    float g8[8];
    #pragma unroll
    for (int j=0;j<8;j++) g8[j] = h2f(obp[e*136 + 2*shw_e + j*16 + 12+t]);
    float lg[6];
    #pragma unroll
    for (int m=0;m<6;m++){
      float s = 0.f;
      #pragma unroll
      for (int j=0;j<8;j++) s = fmaf(g8[j], P[OFF_G1W3 + t*48 + j*6 + m], s);
      lg[m] = s;
    }
    softmaxT<6>(lg);
    float wv[12];
    #pragma unroll
    for (int k=0;k<12;k++)
      wv[k] = (k<9) ? (((k/3)==t) ? lg[k%3] : 0.f) : lg[k-6];
    u32 wp[6];
    #pragma unroll
    for (int p=0;p<6;p++) wp[p] = pkh2(wv[2*p], wv[2*p+1]);
    float s = P[OFF_Tb + t];
    #pragma unroll
    for (int n=0;n<8;n++){
      const u32* rowp = obT + e*68 + shw_e + n*8;
      uint4 A = *(const uint4*)rowp;
      uint2 Bv = *(const uint2*)(rowp + 4);
      float v = dot2(A.x, wp[0], 0.f);
      v = dot2(A.y, wp[1], v);
      v = dot2(A.z, wp[2], v);
      v = dot2(A.w, wp[3], v);
      v = dot2(Bv.x, wp[4], v);
      v = dot2(Bv.y, wp[5], v);
      s = fmaf(v, P[OFF_TW + t*8 + n], s);
    }
    out[t*Btot + blockIdx.x*EPB + e] = 1.f/(1.f + __expf(-s));
  }
}

extern "C" void kernel_launch(void* const* d_in, const int* in_sizes, int n_in,
                              void* d_out, int out_size, void* d_ws, size_t ws_size,
                              hipStream_t stream)
{
  const float* emb = (const float*)d_in[0];
  const int* cat = (const int*)d_in[34];
  float* out = (float*)d_out;
  u32* wsU = (u32*)d_ws;
  float* wsF = (float*)d_ws;
  PSrc S;
  for (int k=0;k<33;k++) S.p[k] = (const float*)d_in[k+1];
  const int B = in_sizes[34] / 9;   // 131072

  cvt_kernel<<<(CVT_TOTAL+255)/256, 256, 0, stream>>>(S, wsU, wsF);
  ple_kernel<<<B/EPB, NT, 0, stream>>>(emb, cat, wsU, wsF, out, B);
}